// Round 2
// baseline (369.177 us; speedup 1.0000x reference)
//
#include <hip/hip_runtime.h>
#include <cmath>
#include <cstdint>

#define N_NODES 100000
#define SAMPLES 16
#define DIM 128
#define NBATCH 8192

#define NPW 4              // nodes per wave
#define WPB 4              // waves per block
#define NODES_PER_BLOCK (NPW * WPB)   // 16

__global__ void zero_flags(int* __restrict__ flags) {
    int i = blockIdx.x * blockDim.x + threadIdx.x;
    if (i < N_NODES) flags[i] = 0;
}

__global__ void mark_flags(const int* __restrict__ batch,
                           const int* __restrict__ nidx,
                           int* __restrict__ flags) {
    int j = blockIdx.x * blockDim.x + threadIdx.x;
    if (j >= NBATCH) return;
    int b = batch[j];
    flags[b] = 1;
    const int* row = nidx + (size_t)b * SAMPLES;
#pragma unroll
    for (int s = 0; s < SAMPLES; ++s) flags[row[s]] = 1;
}

// Block = 256 threads = 4 waves; each wave handles 4 nodes.
// Phase 1: gather self + max-aggregate 16 neighbors into LDS feats[node][256].
// Phase 2: feats(4x256) @ W1(256x128): lane t produces dims 2t, 2t+1 for all
//          4 nodes — each W1 float2 load is reused 4x (cuts L2 weight traffic 4x).
__global__ __launch_bounds__(256) void layer1_kernel(
    const float* __restrict__ x,
    const int* __restrict__ nidx,
    const float* __restrict__ W1,
    const float* __restrict__ b1,
    const int* __restrict__ flags,
    float* __restrict__ h1) {
    const int wave = threadIdx.x >> 6;
    const int t = threadIdx.x & 63;
    const int node0 = (blockIdx.x * WPB + wave) * NPW;   // 6250*16 == 100000 exactly

    __shared__ __align__(16) float feats[WPB][NPW][2 * DIM];
    float* fw = &feats[wave][0][0];

    int fl[NPW];
#pragma unroll
    for (int n = 0; n < NPW; ++n) {
        const int i = node0 + n;
        const int f = flags[i];
        fl[n] = f;
        if (!f) continue;   // wave-uniform branch
        // self features (float2: 8B/lane, 512B/row coalesced)
        const float2 xs = *(const float2*)(x + (size_t)i * DIM + 2 * t);
        fw[n * 2 * DIM + 2 * t] = xs.x;
        fw[n * 2 * DIM + 2 * t + 1] = xs.y;
        // max over 16 sampled neighbors
        float m0 = -1e30f, m1 = -1e30f;
        const int* row = nidx + (size_t)i * SAMPLES;
#pragma unroll
        for (int s = 0; s < SAMPLES; ++s) {
            const int nb = row[s];
            const float2 v = *(const float2*)(x + (size_t)nb * DIM + 2 * t);
            m0 = fmaxf(m0, v.x);
            m1 = fmaxf(m1, v.y);
        }
        fw[n * 2 * DIM + DIM + 2 * t] = m0;
        fw[n * 2 * DIM + DIM + 2 * t + 1] = m1;
    }
    __syncthreads();   // feats visible (uniform across block: branch is per-node, barrier outside)

    // GEMM: h1[i][d] = relu(b1[d] + sum_k feats[k] * W1[k][d]); d = 2t, 2t+1
    const float2 bb = *(const float2*)(b1 + 2 * t);
    float acc0[NPW], acc1[NPW];
#pragma unroll
    for (int n = 0; n < NPW; ++n) { acc0[n] = bb.x; acc1[n] = bb.y; }

    const float* Wp = W1 + 2 * t;
    for (int k = 0; k < 2 * DIM; k += 4) {
        const float2 w0 = *(const float2*)(Wp + (size_t)(k + 0) * DIM);
        const float2 w1 = *(const float2*)(Wp + (size_t)(k + 1) * DIM);
        const float2 w2 = *(const float2*)(Wp + (size_t)(k + 2) * DIM);
        const float2 w3 = *(const float2*)(Wp + (size_t)(k + 3) * DIM);
#pragma unroll
        for (int n = 0; n < NPW; ++n) {
            const float4 f = *(const float4*)&fw[n * 2 * DIM + k];  // LDS b128 broadcast
            acc0[n] += f.x * w0.x; acc1[n] += f.x * w0.y;
            acc0[n] += f.y * w1.x; acc1[n] += f.y * w1.y;
            acc0[n] += f.z * w2.x; acc1[n] += f.z * w2.y;
            acc0[n] += f.w * w3.x; acc1[n] += f.w * w3.y;
        }
    }
#pragma unroll
    for (int n = 0; n < NPW; ++n) {
        if (!fl[n]) continue;
        const int i = node0 + n;
        float2 o;
        o.x = fmaxf(acc0[n], 0.f);
        o.y = fmaxf(acc1[n], 0.f);
        *(float2*)(h1 + (size_t)i * DIM + 2 * t) = o;
    }
}

// Block = 256 threads = 4 waves; each wave handles 4 batch rows.
// SAGE layer 2 (no relu) fused with the 128->64 output projection.
__global__ __launch_bounds__(256) void layer2_kernel(
    const float* __restrict__ h1,
    const int* __restrict__ nidx,
    const int* __restrict__ batch,
    const float* __restrict__ W2,
    const float* __restrict__ b2,
    const float* __restrict__ Wout,
    const float* __restrict__ bout,
    float* __restrict__ out) {
    const int wave = threadIdx.x >> 6;
    const int t = threadIdx.x & 63;
    const int row0 = (blockIdx.x * WPB + wave) * NPW;   // 512*16 == 8192 exactly

    __shared__ __align__(16) float feats[WPB][NPW][2 * DIM];
    __shared__ __align__(16) float h2s[WPB][NPW][DIM];
    float* fw = &feats[wave][0][0];
    float* hw = &h2s[wave][0][0];

    int bnode[NPW];
#pragma unroll
    for (int n = 0; n < NPW; ++n) {
        const int b = batch[row0 + n];
        bnode[n] = b;
        const float2 hs = *(const float2*)(h1 + (size_t)b * DIM + 2 * t);
        fw[n * 2 * DIM + 2 * t] = hs.x;
        fw[n * 2 * DIM + 2 * t + 1] = hs.y;
        float m0 = -1e30f, m1 = -1e30f;
        const int* row = nidx + (size_t)b * SAMPLES;
#pragma unroll
        for (int s = 0; s < SAMPLES; ++s) {
            const int nb = row[s];
            const float2 v = *(const float2*)(h1 + (size_t)nb * DIM + 2 * t);
            m0 = fmaxf(m0, v.x);
            m1 = fmaxf(m1, v.y);
        }
        fw[n * 2 * DIM + DIM + 2 * t] = m0;
        fw[n * 2 * DIM + DIM + 2 * t + 1] = m1;
    }
    __syncthreads();

    // h2 = feats @ W2 + b2  (no relu)
    const float2 bb = *(const float2*)(b2 + 2 * t);
    float acc0[NPW], acc1[NPW];
#pragma unroll
    for (int n = 0; n < NPW; ++n) { acc0[n] = bb.x; acc1[n] = bb.y; }

    const float* Wp = W2 + 2 * t;
    for (int k = 0; k < 2 * DIM; k += 4) {
        const float2 w0 = *(const float2*)(Wp + (size_t)(k + 0) * DIM);
        const float2 w1 = *(const float2*)(Wp + (size_t)(k + 1) * DIM);
        const float2 w2 = *(const float2*)(Wp + (size_t)(k + 2) * DIM);
        const float2 w3 = *(const float2*)(Wp + (size_t)(k + 3) * DIM);
#pragma unroll
        for (int n = 0; n < NPW; ++n) {
            const float4 f = *(const float4*)&fw[n * 2 * DIM + k];
            acc0[n] += f.x * w0.x; acc1[n] += f.x * w0.y;
            acc0[n] += f.y * w1.x; acc1[n] += f.y * w1.y;
            acc0[n] += f.z * w2.x; acc1[n] += f.z * w2.y;
            acc0[n] += f.w * w3.x; acc1[n] += f.w * w3.y;
        }
    }
#pragma unroll
    for (int n = 0; n < NPW; ++n) {
        hw[n * DIM + 2 * t] = acc0[n];
        hw[n * DIM + 2 * t + 1] = acc1[n];
    }
    __syncthreads();

    // out[j][t] = bout[t] + sum_k h2[j][k] * Wout[k][t]; one output dim per lane,
    // each Wout load reused across the wave's 4 rows.
    const float bo = bout[t];
    float accs[NPW];
#pragma unroll
    for (int n = 0; n < NPW; ++n) accs[n] = bo;

    const float* Wo = Wout + t;
    for (int k = 0; k < DIM; k += 2) {
        const float wo0 = Wo[(size_t)(k + 0) * 64];
        const float wo1 = Wo[(size_t)(k + 1) * 64];
#pragma unroll
        for (int n = 0; n < NPW; ++n) {
            const float2 f = *(const float2*)&hw[n * DIM + k];
            accs[n] += f.x * wo0 + f.y * wo1;
        }
    }
#pragma unroll
    for (int n = 0; n < NPW; ++n) {
        out[(size_t)(row0 + n) * 64 + t] = accs[n];
    }
}

extern "C" void kernel_launch(void* const* d_in, const int* in_sizes, int n_in,
                              void* d_out, int out_size, void* d_ws, size_t ws_size,
                              hipStream_t stream) {
    const float* x    = (const float*)d_in[0];
    const int* nidx   = (const int*)d_in[1];
    const int* batch  = (const int*)d_in[2];
    const float* W1   = (const float*)d_in[3];
    const float* b1   = (const float*)d_in[4];
    const float* W2   = (const float*)d_in[5];
    const float* b2   = (const float*)d_in[6];
    const float* Wout = (const float*)d_in[7];
    const float* bout = (const float*)d_in[8];
    float* out        = (float*)d_out;

    // ws layout: [0, 400KB) flags; [1MB, 1MB + 51.2MB) h1 (fp32)
    int* flags = (int*)d_ws;
    float* h1 = (float*)((char*)d_ws + (1 << 20));

    zero_flags<<<(N_NODES + 255) / 256, 256, 0, stream>>>(flags);
    mark_flags<<<(NBATCH + 255) / 256, 256, 0, stream>>>(batch, nidx, flags);
    layer1_kernel<<<N_NODES / NODES_PER_BLOCK, 256, 0, stream>>>(x, nidx, W1, b1, flags, h1);
    layer2_kernel<<<NBATCH / NODES_PER_BLOCK, 256, 0, stream>>>(h1, nidx, batch, W2, b2, Wout, bout, out);
}

// Round 4
// 197.883 us; speedup vs baseline: 1.8656x; 1.8656x over previous
//
#include <hip/hip_runtime.h>
#include <cmath>
#include <cstdint>

#define N_NODES 100000
#define SAMPLES 16
#define DIM 128
#define NBATCH 8192

// LDS feats row stride in f16 elements. Must be mult of 8 (16B-aligned b128);
// 264*2B = 528B = 132 dw ≡ 4 (mod 32) spreads banks acceptably.
#define FSTR 264
#define H2STR 132   // fp32 stride for h2 staging (132*4B ≡ 4 dw mod 32)

typedef _Float16 half8 __attribute__((ext_vector_type(8)));
typedef float floatx4 __attribute__((ext_vector_type(4)));

__device__ __forceinline__ half8 h8max(half8 a, half8 b) {
    half8 r;
#pragma unroll
    for (int i = 0; i < 8; ++i) r[i] = (a[i] > b[i]) ? a[i] : b[i];
    return r;
}

__global__ void zero_flags(int* __restrict__ flags) {
    int i = blockIdx.x * blockDim.x + threadIdx.x;
    if (i < N_NODES) flags[i] = 0;
}

__global__ void mark_flags(const int* __restrict__ batch,
                           const int* __restrict__ nidx,
                           int* __restrict__ flags) {
    int j = blockIdx.x * blockDim.x + threadIdx.x;
    if (j >= NBATCH) return;
    int b = batch[j];
    flags[b] = 1;
    const int* row = nidx + (size_t)b * SAMPLES;
#pragma unroll
    for (int s = 0; s < SAMPLES; ++s) flags[row[s]] = 1;
}

// x fp32 -> fp16, all rows (layer-1 gathers neighbors of flagged nodes,
// which may be unflagged — so convert everything).
__global__ __launch_bounds__(256) void cvt_x(const float* __restrict__ x,
                                             _Float16* __restrict__ xh) {
    const int tid = blockIdx.x * blockDim.x + threadIdx.x;  // 8 elems/thread
    const size_t base = (size_t)tid * 8;
    if (base >= (size_t)N_NODES * DIM) return;
    const float4* xp = (const float4*)(x + base);
    const float4 a = xp[0], b = xp[1];
    half8 v;
    v[0] = (_Float16)a.x; v[1] = (_Float16)a.y;
    v[2] = (_Float16)a.z; v[3] = (_Float16)a.w;
    v[4] = (_Float16)b.x; v[5] = (_Float16)b.y;
    v[6] = (_Float16)b.z; v[7] = (_Float16)b.w;
    *(half8*)(xh + base) = v;
}

// W[256][128] fp32 -> f16 B-fragment order for mfma_f32_16x16x32_f16:
// frag (kb,nb,lane) holds B[k = kb*32 + (lane>>4)*8 + j][n = nb*16 + (lane&15)]
__global__ __launch_bounds__(256) void swizzle_w(const float* __restrict__ W1,
                                                 const float* __restrict__ W2,
                                                 _Float16* __restrict__ W1sw,
                                                 _Float16* __restrict__ W2sw) {
    const int tid = blockIdx.x * blockDim.x + threadIdx.x;  // [0, 8192)
    const int which = tid >> 12;
    const int r = tid & 4095;
    const int kb = r >> 9, nb = (r >> 6) & 7, lane = r & 63;
    const int q = lane >> 4, c = lane & 15;
    const float* W = which ? W2 : W1;
    _Float16* O = which ? W2sw : W1sw;
    const int k0 = kb * 32 + q * 8;
    const int n = nb * 16 + c;
    half8 v;
#pragma unroll
    for (int j = 0; j < 8; ++j) v[j] = (_Float16)W[(size_t)(k0 + j) * DIM + n];
    *(half8*)(O + (size_t)r * 8) = v;
}

// Block = 256 (4 waves); each wave owns 16 nodes: gather+max into its private
// LDS feats[16][264] (f16), then 16x128 = 8 MFMA tiles over K=256.
__global__ __launch_bounds__(256) void layer1_kernel(
    const _Float16* __restrict__ xh,
    const int* __restrict__ nidx,
    const _Float16* __restrict__ W1sw,
    const float* __restrict__ b1,
    const int* __restrict__ flags,
    _Float16* __restrict__ h1h) {
    const int wave = threadIdx.x >> 6;
    const int lane = threadIdx.x & 63;
    const int q = lane >> 4;   // 0..3
    const int c = lane & 15;   // 0..15
    const int w0 = blockIdx.x * 64 + wave * 16;

    __shared__ __align__(16) _Float16 feats[4][16 * FSTR];
    _Float16* fw = feats[wave];

    // ---- gather: node-groups of 4 (g = q), lane c covers dims c*8..c*8+7 ----
#pragma unroll
    for (int ng = 0; ng < 4; ++ng) {
        const int m = ng * 4 + q;
        const int i = w0 + m;
        const bool valid = (i < N_NODES) && flags[i];
        if (valid) {
            const half8 s = *(const half8*)(xh + (size_t)i * DIM + c * 8);
            *(half8*)(fw + m * FSTR + c * 8) = s;
            half8 mx;
#pragma unroll
            for (int e = 0; e < 8; ++e) mx[e] = (_Float16)(-60000.f);
            const int* row = nidx + (size_t)i * SAMPLES;
#pragma unroll
            for (int s2 = 0; s2 < SAMPLES; ++s2) {
                const int nb = row[s2];
                const half8 v = *(const half8*)(xh + (size_t)nb * DIM + c * 8);
                mx = h8max(mx, v);
            }
            *(half8*)(fw + m * FSTR + DIM + c * 8) = mx;
        }
    }
    __syncthreads();

    // ---- MFMA: A[m=c][k=q*8+j], D[m=q*4+r][n=c] ----
    floatx4 acc[8];
#pragma unroll
    for (int nb = 0; nb < 8; ++nb) acc[nb] = (floatx4){0.f, 0.f, 0.f, 0.f};

#pragma unroll
    for (int kb = 0; kb < 8; ++kb) {
        const half8 a = *(const half8*)(fw + c * FSTR + kb * 32 + q * 8);
#pragma unroll
        for (int nb = 0; nb < 8; ++nb) {
            const half8 b = *(const half8*)(W1sw + (size_t)((kb * 8 + nb) * 64 + lane) * 8);
            acc[nb] = __builtin_amdgcn_mfma_f32_16x16x32_f16(a, b, acc[nb], 0, 0, 0);
        }
    }

    // ---- epilogue: bias + relu + f16 store ----
    int fl[4];
#pragma unroll
    for (int r = 0; r < 4; ++r) {
        const int i = w0 + q * 4 + r;
        fl[r] = (i < N_NODES) && flags[i];
    }
#pragma unroll
    for (int nb = 0; nb < 8; ++nb) {
        const int n = nb * 16 + c;
        const float bias = b1[n];
#pragma unroll
        for (int r = 0; r < 4; ++r) {
            if (!fl[r]) continue;
            const int i = w0 + q * 4 + r;
            const float v = fmaxf(acc[nb][r] + bias, 0.f);
            h1h[(size_t)i * DIM + n] = (_Float16)v;
        }
    }
}

// One wave per block; 16 batch rows: SAGE layer2 (MFMA) + fused proj_out.
__global__ __launch_bounds__(64) void layer2_kernel(
    const _Float16* __restrict__ h1h,
    const int* __restrict__ nidx,
    const int* __restrict__ batch,
    const _Float16* __restrict__ W2sw,
    const float* __restrict__ b2,
    const float* __restrict__ Wout,
    const float* __restrict__ bout,
    float* __restrict__ out) {
    const int lane = threadIdx.x;
    const int q = lane >> 4, c = lane & 15;
    const int w0 = blockIdx.x * 16;

    __shared__ __align__(16) _Float16 feats[16 * FSTR];
    __shared__ __align__(16) float h2s[16 * H2STR];

#pragma unroll
    for (int ng = 0; ng < 4; ++ng) {
        const int m = ng * 4 + q;
        const int node = batch[w0 + m];
        const half8 s = *(const half8*)(h1h + (size_t)node * DIM + c * 8);
        *(half8*)(feats + m * FSTR + c * 8) = s;
        half8 mx;
#pragma unroll
        for (int e = 0; e < 8; ++e) mx[e] = (_Float16)(-60000.f);
        const int* row = nidx + (size_t)node * SAMPLES;
#pragma unroll
        for (int s2 = 0; s2 < SAMPLES; ++s2) {
            const int nb = row[s2];
            const half8 v = *(const half8*)(h1h + (size_t)nb * DIM + c * 8);
            mx = h8max(mx, v);
        }
        *(half8*)(feats + m * FSTR + DIM + c * 8) = mx;
    }
    __syncthreads();

    floatx4 acc[8];
#pragma unroll
    for (int nb = 0; nb < 8; ++nb) acc[nb] = (floatx4){0.f, 0.f, 0.f, 0.f};

#pragma unroll
    for (int kb = 0; kb < 8; ++kb) {
        const half8 a = *(const half8*)(feats + c * FSTR + kb * 32 + q * 8);
#pragma unroll
        for (int nb = 0; nb < 8; ++nb) {
            const half8 b = *(const half8*)(W2sw + (size_t)((kb * 8 + nb) * 64 + lane) * 8);
            acc[nb] = __builtin_amdgcn_mfma_f32_16x16x32_f16(a, b, acc[nb], 0, 0, 0);
        }
    }

    // h2 (no relu) -> LDS fp32
#pragma unroll
    for (int nb = 0; nb < 8; ++nb) {
        const float bias = b2[nb * 16 + c];
#pragma unroll
        for (int r = 0; r < 4; ++r)
            h2s[(q * 4 + r) * H2STR + nb * 16 + c] = acc[nb][r] + bias;
    }
    __syncthreads();

    // proj_out: lane = output dim t (64); 16 rows
    float accs[16];
    const float bo = bout[lane];
#pragma unroll
    for (int m = 0; m < 16; ++m) accs[m] = bo;
    for (int k4 = 0; k4 < DIM; k4 += 4) {
        float wv[4];
#pragma unroll
        for (int j = 0; j < 4; ++j) wv[j] = Wout[(size_t)(k4 + j) * 64 + lane];
#pragma unroll
        for (int m = 0; m < 16; ++m) {
            const float4 f = *(const float4*)&h2s[m * H2STR + k4];
            accs[m] += f.x * wv[0] + f.y * wv[1] + f.z * wv[2] + f.w * wv[3];
        }
    }
#pragma unroll
    for (int m = 0; m < 16; ++m)
        out[(size_t)(w0 + m) * 64 + lane] = accs[m];
}

extern "C" void kernel_launch(void* const* d_in, const int* in_sizes, int n_in,
                              void* d_out, int out_size, void* d_ws, size_t ws_size,
                              hipStream_t stream) {
    const float* x    = (const float*)d_in[0];
    const int* nidx   = (const int*)d_in[1];
    const int* batch  = (const int*)d_in[2];
    const float* W1   = (const float*)d_in[3];
    const float* b1   = (const float*)d_in[4];
    const float* W2   = (const float*)d_in[5];
    const float* b2   = (const float*)d_in[6];
    const float* Wout = (const float*)d_in[7];
    const float* bout = (const float*)d_in[8];
    float* out        = (float*)d_out;

    // ws layout (bytes):
    //   [0, 400000)                flags
    //   [409600, 475136)           W1sw f16 (64 KB)
    //   [475136, 540672)           W2sw f16 (64 KB)
    //   [540672, 26140672)         xh   f16 (25.6 MB)
    //   [26140672, 51740672)       h1h  f16 (25.6 MB)
    int* flags      = (int*)d_ws;
    _Float16* W1sw  = (_Float16*)((char*)d_ws + 409600);
    _Float16* W2sw  = (_Float16*)((char*)d_ws + 475136);
    _Float16* xh    = (_Float16*)((char*)d_ws + 540672);
    _Float16* h1h   = (_Float16*)((char*)d_ws + 26140672);

    zero_flags<<<(N_NODES + 255) / 256, 256, 0, stream>>>(flags);
    mark_flags<<<(NBATCH + 255) / 256, 256, 0, stream>>>(batch, nidx, flags);
    cvt_x<<<(N_NODES * DIM / 8 + 255) / 256, 256, 0, stream>>>(x, xh);
    swizzle_w<<<32, 256, 0, stream>>>(W1, W2, W1sw, W2sw);
    layer1_kernel<<<(N_NODES + 63) / 64, 256, 0, stream>>>(xh, nidx, W1sw, b1, flags, h1h);
    layer2_kernel<<<NBATCH / 16, 64, 0, stream>>>(h1h, nidx, batch, W2sw, b2, Wout, bout, out);
}

// Round 5
// 194.492 us; speedup vs baseline: 1.8982x; 1.0174x over previous
//
#include <hip/hip_runtime.h>
#include <cmath>
#include <cstdint>

#define N_NODES 100000
#define SAMPLES 16
#define DIM 128
#define NBATCH 8192

#define FSTR 264    // f16 LDS row stride (16B-aligned, non-pow2 bank spread)
#define H2STR 132   // fp32 LDS row stride

typedef _Float16 half8 __attribute__((ext_vector_type(8)));
typedef float floatx4 __attribute__((ext_vector_type(4)));

__device__ __forceinline__ half8 h8max(half8 a, half8 b) {
    half8 r;
#pragma unroll
    for (int i = 0; i < 8; ++i) r[i] = (a[i] > b[i]) ? a[i] : b[i];
    return r;
}

// Fused setup: cvt_x (blocks [0,6250)), zero_flags ([6250,6641)), swizzle_w ([6641,6673))
__global__ __launch_bounds__(256) void setup_kernel(
    const float* __restrict__ x,
    const float* __restrict__ W1,
    const float* __restrict__ W2,
    int* __restrict__ flags,
    _Float16* __restrict__ xh,
    _Float16* __restrict__ W1sw,
    _Float16* __restrict__ W2sw) {
    const int bid = blockIdx.x;
    if (bid < 6250) {
        // x fp32 -> f16, 8 elems/thread; 6250*256*8 == 12.8M == N_NODES*DIM
        const size_t base = ((size_t)bid * 256 + threadIdx.x) * 8;
        const float4* xp = (const float4*)(x + base);
        const float4 a = xp[0], b = xp[1];
        half8 v;
        v[0] = (_Float16)a.x; v[1] = (_Float16)a.y;
        v[2] = (_Float16)a.z; v[3] = (_Float16)a.w;
        v[4] = (_Float16)b.x; v[5] = (_Float16)b.y;
        v[6] = (_Float16)b.z; v[7] = (_Float16)b.w;
        *(half8*)(xh + base) = v;
    } else if (bid < 6641) {
        const int i = (bid - 6250) * 256 + threadIdx.x;
        if (i < N_NODES) flags[i] = 0;
    } else {
        // W[256][128] -> f16 B-fragment order for mfma_f32_16x16x32_f16
        const int tid = (bid - 6641) * 256 + threadIdx.x;  // [0, 8192)
        const int which = tid >> 12;
        const int r = tid & 4095;
        const int kb = r >> 9, nb = (r >> 6) & 7, lane = r & 63;
        const int q = lane >> 4, c = lane & 15;
        const float* W = which ? W2 : W1;
        _Float16* O = which ? W2sw : W1sw;
        const int k0 = kb * 32 + q * 8;
        const int n = nb * 16 + c;
        half8 v;
#pragma unroll
        for (int j = 0; j < 8; ++j) v[j] = (_Float16)W[(size_t)(k0 + j) * DIM + n];
        *(half8*)(O + (size_t)r * 8) = v;
    }
}

__global__ __launch_bounds__(256) void mark_flags(const int* __restrict__ batch,
                                                  const int* __restrict__ nidx,
                                                  int* __restrict__ flags) {
    int j = blockIdx.x * blockDim.x + threadIdx.x;
    if (j >= NBATCH) return;
    int b = batch[j];
    flags[b] = 1;
    const int* row = nidx + (size_t)b * SAMPLES;
#pragma unroll
    for (int s = 0; s < SAMPLES; ++s) flags[row[s]] = 1;
}

// Block = 256 (4 waves); each wave owns 16 nodes. Gather: hoisted flags,
// pipelined nidx loads, 17 row-loads in flight then tree-max. MFMA K=256.
__global__ __launch_bounds__(256) void layer1_kernel(
    const _Float16* __restrict__ xh,
    const int* __restrict__ nidx,
    const _Float16* __restrict__ W1sw,
    const float* __restrict__ b1,
    const int* __restrict__ flags,
    _Float16* __restrict__ h1h) {
    const int wave = threadIdx.x >> 6;
    const int lane = threadIdx.x & 63;
    const int q = lane >> 4;
    const int c = lane & 15;
    const int w0 = blockIdx.x * 64 + wave * 16;

    __shared__ __align__(16) _Float16 feats[4][16 * FSTR];
    _Float16* fw = feats[wave];

    // hoisted flags (4 independent loads)
    int fl[4];
#pragma unroll
    for (int ng = 0; ng < 4; ++ng) {
        const int i = w0 + ng * 4 + q;
        fl[ng] = (i < N_NODES) ? flags[i] : 0;
    }
    // pipelined neighbor-index rows
    int4 cur0, cur1, cur2, cur3;
    {
        int i = w0 + q; if (i >= N_NODES) i = N_NODES - 1;
        const int4* rp = (const int4*)(nidx + (size_t)i * SAMPLES);
        cur0 = rp[0]; cur1 = rp[1]; cur2 = rp[2]; cur3 = rp[3];
    }
    const size_t co = (size_t)c * 8;
#pragma unroll
    for (int ng = 0; ng < 4; ++ng) {
        int4 nx0, nx1, nx2, nx3;
        if (ng < 3) {
            int i = w0 + (ng + 1) * 4 + q; if (i >= N_NODES) i = N_NODES - 1;
            const int4* rp = (const int4*)(nidx + (size_t)i * SAMPLES);
            nx0 = rp[0]; nx1 = rp[1]; nx2 = rp[2]; nx3 = rp[3];
        }
        if (fl[ng]) {
            const int m = ng * 4 + q;
            const int i = w0 + m;
            const half8 self = *(const half8*)(xh + (size_t)i * DIM + co);
            *(half8*)(fw + m * FSTR + c * 8) = self;
            half8 v[16];
            v[0]  = *(const half8*)(xh + (size_t)cur0.x * DIM + co);
            v[1]  = *(const half8*)(xh + (size_t)cur0.y * DIM + co);
            v[2]  = *(const half8*)(xh + (size_t)cur0.z * DIM + co);
            v[3]  = *(const half8*)(xh + (size_t)cur0.w * DIM + co);
            v[4]  = *(const half8*)(xh + (size_t)cur1.x * DIM + co);
            v[5]  = *(const half8*)(xh + (size_t)cur1.y * DIM + co);
            v[6]  = *(const half8*)(xh + (size_t)cur1.z * DIM + co);
            v[7]  = *(const half8*)(xh + (size_t)cur1.w * DIM + co);
            v[8]  = *(const half8*)(xh + (size_t)cur2.x * DIM + co);
            v[9]  = *(const half8*)(xh + (size_t)cur2.y * DIM + co);
            v[10] = *(const half8*)(xh + (size_t)cur2.z * DIM + co);
            v[11] = *(const half8*)(xh + (size_t)cur2.w * DIM + co);
            v[12] = *(const half8*)(xh + (size_t)cur3.x * DIM + co);
            v[13] = *(const half8*)(xh + (size_t)cur3.y * DIM + co);
            v[14] = *(const half8*)(xh + (size_t)cur3.z * DIM + co);
            v[15] = *(const half8*)(xh + (size_t)cur3.w * DIM + co);
#pragma unroll
            for (int s = 0; s < 8; ++s) v[s] = h8max(v[s], v[s + 8]);
#pragma unroll
            for (int s = 0; s < 4; ++s) v[s] = h8max(v[s], v[s + 4]);
            v[0] = h8max(h8max(v[0], v[1]), h8max(v[2], v[3]));
            *(half8*)(fw + m * FSTR + DIM + c * 8) = v[0];
        }
        if (ng < 3) { cur0 = nx0; cur1 = nx1; cur2 = nx2; cur3 = nx3; }
    }
    __syncthreads();

    // MFMA: A[m=c][k=q*8+j], D[m=q*4+r][n=c]
    floatx4 acc[8];
#pragma unroll
    for (int nb = 0; nb < 8; ++nb) acc[nb] = (floatx4){0.f, 0.f, 0.f, 0.f};
#pragma unroll
    for (int kb = 0; kb < 8; ++kb) {
        const half8 a = *(const half8*)(fw + c * FSTR + kb * 32 + q * 8);
#pragma unroll
        for (int nb = 0; nb < 8; ++nb) {
            const half8 b = *(const half8*)(W1sw + (size_t)((kb * 8 + nb) * 64 + lane) * 8);
            acc[nb] = __builtin_amdgcn_mfma_f32_16x16x32_f16(a, b, acc[nb], 0, 0, 0);
        }
    }
    // epilogue: bias + relu + f16 store (flagged rows only)
#pragma unroll
    for (int nb = 0; nb < 8; ++nb) {
        const int n = nb * 16 + c;
        const float bias = b1[n];
#pragma unroll
        for (int r = 0; r < 4; ++r) {
            const int m = q * 4 + r;
            if (!fl[m >> 2]) continue;   // m>>2 == ng owning node m? no — recompute
        }
    }
    // NOTE: flag per store must key on the stored row m = q*4+r, whose ng is (q*4+r)/4 ... 
    // recompute directly from flags to keep it simple and correct:
#pragma unroll
    for (int nb = 0; nb < 8; ++nb) {
        const int n = nb * 16 + c;
        const float bias = b1[n];
#pragma unroll
        for (int r = 0; r < 4; ++r) {
            const int i = w0 + q * 4 + r;
            if (i >= N_NODES || !flags[i]) continue;
            const float v = fmaxf(acc[nb][r] + bias, 0.f);
            h1h[(size_t)i * DIM + n] = (_Float16)v;
        }
    }
}

// Block = 256 (4 waves) per 16 batch rows. 16-lane group (wave,q) gathers one
// row; waves split MFMA by N (2 tiles each) and proj rows by wave.
__global__ __launch_bounds__(256) void layer2_kernel(
    const _Float16* __restrict__ h1h,
    const int* __restrict__ nidx,
    const int* __restrict__ batch,
    const _Float16* __restrict__ W2sw,
    const float* __restrict__ b2,
    const float* __restrict__ Wout,
    const float* __restrict__ bout,
    float* __restrict__ out) {
    const int wave = threadIdx.x >> 6;
    const int lane = threadIdx.x & 63;
    const int q = lane >> 4, c = lane & 15;
    const int w0 = blockIdx.x * 16;

    __shared__ __align__(16) _Float16 feats[16 * FSTR];
    __shared__ __align__(16) float h2s[16 * H2STR];

    // ---- gather: group (wave,q) handles row m = wave*4+q ----
    {
        const int m = wave * 4 + q;
        const int node = batch[w0 + m];
        const size_t co = (size_t)c * 8;
        const int4* rp = (const int4*)(nidx + (size_t)node * SAMPLES);
        const int4 i0 = rp[0], i1 = rp[1], i2 = rp[2], i3 = rp[3];
        const half8 self = *(const half8*)(h1h + (size_t)node * DIM + co);
        *(half8*)(feats + m * FSTR + c * 8) = self;
        half8 v[16];
        v[0]  = *(const half8*)(h1h + (size_t)i0.x * DIM + co);
        v[1]  = *(const half8*)(h1h + (size_t)i0.y * DIM + co);
        v[2]  = *(const half8*)(h1h + (size_t)i0.z * DIM + co);
        v[3]  = *(const half8*)(h1h + (size_t)i0.w * DIM + co);
        v[4]  = *(const half8*)(h1h + (size_t)i1.x * DIM + co);
        v[5]  = *(const half8*)(h1h + (size_t)i1.y * DIM + co);
        v[6]  = *(const half8*)(h1h + (size_t)i1.z * DIM + co);
        v[7]  = *(const half8*)(h1h + (size_t)i1.w * DIM + co);
        v[8]  = *(const half8*)(h1h + (size_t)i2.x * DIM + co);
        v[9]  = *(const half8*)(h1h + (size_t)i2.y * DIM + co);
        v[10] = *(const half8*)(h1h + (size_t)i2.z * DIM + co);
        v[11] = *(const half8*)(h1h + (size_t)i2.w * DIM + co);
        v[12] = *(const half8*)(h1h + (size_t)i3.x * DIM + co);
        v[13] = *(const half8*)(h1h + (size_t)i3.y * DIM + co);
        v[14] = *(const half8*)(h1h + (size_t)i3.z * DIM + co);
        v[15] = *(const half8*)(h1h + (size_t)i3.w * DIM + co);
#pragma unroll
        for (int s = 0; s < 8; ++s) v[s] = h8max(v[s], v[s + 8]);
#pragma unroll
        for (int s = 0; s < 4; ++s) v[s] = h8max(v[s], v[s + 4]);
        v[0] = h8max(h8max(v[0], v[1]), h8max(v[2], v[3]));
        *(half8*)(feats + m * FSTR + DIM + c * 8) = v[0];
    }
    __syncthreads();

    // ---- MFMA: wave computes nb = 2*wave, 2*wave+1 over full K ----
    const int nb0 = wave * 2;
    floatx4 acc[2];
    acc[0] = (floatx4){0.f, 0.f, 0.f, 0.f};
    acc[1] = (floatx4){0.f, 0.f, 0.f, 0.f};
#pragma unroll
    for (int kb = 0; kb < 8; ++kb) {
        const half8 a = *(const half8*)(feats + c * FSTR + kb * 32 + q * 8);
#pragma unroll
        for (int j = 0; j < 2; ++j) {
            const half8 b = *(const half8*)(W2sw + (size_t)((kb * 8 + nb0 + j) * 64 + lane) * 8);
            acc[j] = __builtin_amdgcn_mfma_f32_16x16x32_f16(a, b, acc[j], 0, 0, 0);
        }
    }
#pragma unroll
    for (int j = 0; j < 2; ++j) {
        const int n = (nb0 + j) * 16 + c;
        const float bias = b2[n];
#pragma unroll
        for (int r = 0; r < 4; ++r)
            h2s[(q * 4 + r) * H2STR + n] = acc[j][r] + bias;
    }
    __syncthreads();

    // ---- proj_out: wave handles rows wave*4..+3; lane = output dim ----
    float accs[4];
    const float bo = bout[lane];
#pragma unroll
    for (int r = 0; r < 4; ++r) accs[r] = bo;
    for (int k4 = 0; k4 < DIM; k4 += 4) {
        float wv[4];
#pragma unroll
        for (int j = 0; j < 4; ++j) wv[j] = Wout[(size_t)(k4 + j) * 64 + lane];
#pragma unroll
        for (int r = 0; r < 4; ++r) {
            const float4 f = *(const float4*)&h2s[(wave * 4 + r) * H2STR + k4];
            accs[r] += f.x * wv[0] + f.y * wv[1] + f.z * wv[2] + f.w * wv[3];
        }
    }
#pragma unroll
    for (int r = 0; r < 4; ++r)
        out[(size_t)(w0 + wave * 4 + r) * 64 + lane] = accs[r];
}

extern "C" void kernel_launch(void* const* d_in, const int* in_sizes, int n_in,
                              void* d_out, int out_size, void* d_ws, size_t ws_size,
                              hipStream_t stream) {
    const float* x    = (const float*)d_in[0];
    const int* nidx   = (const int*)d_in[1];
    const int* batch  = (const int*)d_in[2];
    const float* W1   = (const float*)d_in[3];
    const float* b1   = (const float*)d_in[4];
    const float* W2   = (const float*)d_in[5];
    const float* b2   = (const float*)d_in[6];
    const float* Wout = (const float*)d_in[7];
    const float* bout = (const float*)d_in[8];
    float* out        = (float*)d_out;

    // ws layout (bytes):
    //   [0, 400000)           flags
    //   [409600, 475136)      W1sw f16
    //   [475136, 540672)      W2sw f16
    //   [540672, 26140672)    xh   f16
    //   [26140672, 51740672)  h1h  f16
    int* flags      = (int*)d_ws;
    _Float16* W1sw  = (_Float16*)((char*)d_ws + 409600);
    _Float16* W2sw  = (_Float16*)((char*)d_ws + 475136);
    _Float16* xh    = (_Float16*)((char*)d_ws + 540672);
    _Float16* h1h   = (_Float16*)((char*)d_ws + 26140672);

    setup_kernel<<<6673, 256, 0, stream>>>(x, W1, W2, flags, xh, W1sw, W2sw);
    mark_flags<<<32, 256, 0, stream>>>(batch, nidx, flags);
    layer1_kernel<<<(N_NODES + 63) / 64, 256, 0, stream>>>(xh, nidx, W1sw, b1, flags, h1h);
    layer2_kernel<<<NBATCH / 16, 256, 0, stream>>>(h1h, nidx, batch, W2sw, b2, Wout, bout, out);
}